// Round 5
// baseline (550.207 us; speedup 1.0000x reference)
//
#include <hip/hip_runtime.h>

#define KB 8
#define KN 4096
#define KNA 64
#define KH 12
#define KD 32
#define KC 384
#define KC2 768
#define KSCALE 0.17677669529663688f

typedef __bf16 bf16x8 __attribute__((ext_vector_type(8)));
typedef float  f32x4  __attribute__((ext_vector_type(4)));

static __device__ __forceinline__ unsigned short f2bf(float f) {
    unsigned int u = __builtin_bit_cast(unsigned int, f);
    u += 0x7FFFu + ((u >> 16) & 1u);
    return (unsigned short)(u >> 16);
}

static __device__ __forceinline__ void gld_lds16(const unsigned short* g, unsigned short* l) {
    __builtin_amdgcn_global_load_lds(
        (const __attribute__((address_space(1))) unsigned int*)g,
        (__attribute__((address_space(3))) unsigned int*)l, 16, 0, 0);
}

#define MFMA_16x16x32 __builtin_amdgcn_mfma_f32_16x16x32_bf16

// ---------------- K0: Kag = agent@Wk_ag + bk ; Qa = agent@Wq_ag + bq
__global__ __launch_bounds__(256) void k_agent_proj(
    const float* __restrict__ agent,
    const float* __restrict__ Wk_ag, const float* __restrict__ bk_ag,
    const float* __restrict__ Wq_ag, const float* __restrict__ bq_ag,
    float* __restrict__ Kag, float* __restrict__ Qa)
{
    __shared__ float a_lds[8][KC];
    const int tid = threadIdx.x;
    const int rg  = blockIdx.x;
    const float* W    = blockIdx.y ? Wq_ag : Wk_ag;
    const float* bias = blockIdx.y ? bq_ag : bk_ag;
    float* dst        = blockIdx.y ? Qa    : Kag;

    const float4* src4 = reinterpret_cast<const float4*>(agent) + (size_t)rg * 768;
    float4* al4 = reinterpret_cast<float4*>(&a_lds[0][0]);
    #pragma unroll
    for (int l = 0; l < 3; ++l) al4[tid + l*256] = src4[tid + l*256];
    __syncthreads();

    float acc[8][3] = {};
    for (int c = 0; c < KC; ++c) {
        float w0 = W[(size_t)c*KC2 + tid];
        float w1 = W[(size_t)c*KC2 + tid + 256];
        float w2 = W[(size_t)c*KC2 + tid + 512];
        #pragma unroll
        for (int r = 0; r < 8; ++r) {
            float a = a_lds[r][c];
            acc[r][0] = fmaf(a, w0, acc[r][0]);
            acc[r][1] = fmaf(a, w1, acc[r][1]);
            acc[r][2] = fmaf(a, w2, acc[r][2]);
        }
    }
    float b0 = bias[tid], b1 = bias[tid+256], b2 = bias[tid+512];
    #pragma unroll
    for (int r = 0; r < 8; ++r) {
        size_t base = (size_t)(rg*8 + r) * KC2;
        dst[base + tid      ] = acc[r][0] + b0;
        dst[base + tid + 256] = acc[r][1] + b1;
        dst[base + tid + 512] = acc[r][2] + b2;
    }
}

// ---------------- transpose Wk_hf [384,768] -> WkT [768,384] (f32)
__global__ __launch_bounds__(256) void k_transpose(
    const float* __restrict__ Win, float* __restrict__ Wout)
{
    __shared__ float tile[32][33];
    const int tx = threadIdx.x, ty = threadIdx.y;
    const int j0 = blockIdx.x * 32, c0 = blockIdx.y * 32;
    #pragma unroll
    for (int yy = 0; yy < 4; ++yy)
        tile[ty + yy*8][tx] = Win[(size_t)(c0 + ty + yy*8)*KC2 + j0 + tx];
    __syncthreads();
    #pragma unroll
    for (int yy = 0; yy < 4; ++yy)
        Wout[(size_t)(j0 + ty + yy*8)*KC + c0 + tx] = tile[tx][ty + yy*8];
}

// ---------------- tcastT: src f32 [R][C] -> dstT bf16 frag-major [(r>>5)][C][32]
//                  optional dstRM: bf16 row-major, 16B-granule XOR-swizzled (g^(r&7))
__global__ __launch_bounds__(256) void k_tcastT(
    const float* __restrict__ src, unsigned short* __restrict__ dstT,
    unsigned short* __restrict__ dstRM,
    int R, int C, long sstride, long dTstride, long dRMstride)
{
    __shared__ unsigned short lds[64][80];
    const int t = threadIdx.x;
    const int r0 = blockIdx.x * 64, c0 = blockIdx.y * 64;
    const float* s = src + (size_t)blockIdx.z * sstride;
    #pragma unroll
    for (int i = 0; i < 16; ++i) {
        int f = t + i*256; int rr = f >> 6, cc = f & 63;
        lds[rr][cc] = f2bf(s[(size_t)(r0+rr)*C + c0 + cc]);
    }
    __syncthreads();
    if (dstT) {
        unsigned short* dT = dstT + (size_t)blockIdx.z * dTstride;
        #pragma unroll
        for (int i = 0; i < 8; ++i) {
            int o = t + i*256;
            int chunk = o >> 10, c = (o >> 4) & 63, pair = o & 15;
            int r = chunk*32 + pair*2;
            unsigned int v = (unsigned int)lds[r][c] | ((unsigned int)lds[r+1][c] << 16);
            size_t off = ((size_t)((r0>>5) + chunk)*C + c0 + c)*32 + pair*2;
            *reinterpret_cast<unsigned int*>(dT + off) = v;
        }
    }
    if (dstRM) {
        unsigned short* dR = dstRM + (size_t)blockIdx.z * dRMstride;
        #pragma unroll
        for (int i = 0; i < 2; ++i) {
            int idx = t*2 + i;
            int n = idx >> 3, gt = idx & 7;
            int g = (c0 >> 3) + gt;
            int slot = g ^ ((r0 + n) & 7);
            *reinterpret_cast<bf16x8*>(dR + (size_t)(r0+n)*C + slot*8) =
                *reinterpret_cast<const bf16x8*>(&lds[n][gt*8]);
        }
    }
}

// ---------------- K1: E[b][c][hm]  (f32)
__global__ __launch_bounds__(256) void k_build_E(
    const float* __restrict__ Wq_lf, const float* __restrict__ Kag,
    const float* __restrict__ wa, float* __restrict__ E)
{
    __shared__ float w_lds[8][KC2];
    const int tid = threadIdx.x;
    const int cg = blockIdx.x;
    const int b  = blockIdx.y;
    const float4* src = reinterpret_cast<const float4*>(Wq_lf + (size_t)cg*8*KC2);
    float4* dst4 = reinterpret_cast<float4*>(&w_lds[0][0]);
    #pragma unroll
    for (int l = 0; l < 6; ++l) dst4[tid + l*256] = src[tid + l*256];
    __syncthreads();
    const float s0 = KSCALE * wa[0], s1 = KSCALE * wa[1];
    float acc[8][3] = {};
    #pragma unroll
    for (int j = 0; j < 3; ++j) {
        const int hm = tid + j*256;
        const int h = hm >> 6, m = hm & 63;
        const float* kp = Kag + (size_t)(b*KNA + m)*KC2;
        const int base1 = h*KD, base2 = KC + h*KD;
        for (int d = 0; d < KD; ++d) {
            float a1 = kp[base1 + d] * s0;
            float a2 = kp[base2 + d] * s1;
            #pragma unroll
            for (int cr = 0; cr < 8; ++cr)
                acc[cr][j] += w_lds[cr][base1+d]*a1 + w_lds[cr][base2+d]*a2;
        }
    }
    #pragma unroll
    for (int cr = 0; cr < 8; ++cr)
        #pragma unroll
        for (int j = 0; j < 3; ++j)
            E[((size_t)b*KC + cg*8 + cr)*KC2 + tid + j*256] = acc[cr][j];
}

// ---------------- K2b: F_bf[b][hm][c] bf16 row-major
__global__ __launch_bounds__(128) void k_build_F(
    const float* __restrict__ WkT, const float* __restrict__ Qa,
    const float* __restrict__ wb, unsigned short* __restrict__ Fbf)
{
    __shared__ float q_lds[8][64];
    const int tid = threadIdx.x;
    const int g = blockIdx.x;
    const int b = blockIdx.y;
    const int h = (g*8) >> 6;
    const float t0 = KSCALE*wb[0], t1 = KSCALE*wb[1];
    #pragma unroll
    for (int l = 0; l < 4; ++l) {
        int v = tid + l*128;
        int i = v >> 6, d = v & 63;
        int m = (g*8 + i) & 63;
        int jj   = (d < KD) ? (h*KD + d) : (KC + h*KD + d - KD);
        float cf = (d < KD) ? t0 : t1;
        q_lds[i][d] = cf * Qa[(size_t)(b*KNA + m)*KC2 + jj];
    }
    __syncthreads();
    float acc[8][3] = {};
    for (int d = 0; d < 64; ++d) {
        int row = (d < KD) ? (h*KD + d) : (KC + h*KD + d - KD);
        const float* wr = WkT + (size_t)row*KC;
        float w0 = wr[tid], w1 = wr[tid+128], w2 = wr[tid+256];
        #pragma unroll
        for (int i = 0; i < 8; ++i) {
            float q = q_lds[i][d];
            acc[i][0] = fmaf(q, w0, acc[i][0]);
            acc[i][1] = fmaf(q, w1, acc[i][1]);
            acc[i][2] = fmaf(q, w2, acc[i][2]);
        }
    }
    #pragma unroll
    for (int i = 0; i < 8; ++i)
        #pragma unroll
        for (int l = 0; l < 3; ++l)
            Fbf[((size_t)b*KC2 + g*8 + i)*KC + tid + l*128] = f2bf(acc[i][l]);
}

// ---------------- K1c: bias constants cA, cB
__global__ __launch_bounds__(256) void k_build_c(
    const float* __restrict__ bq_lf, const float* __restrict__ Kag,
    const float* __restrict__ wa, const float* __restrict__ ba,
    const float* __restrict__ bk_hf, const float* __restrict__ Qa,
    const float* __restrict__ wb, const float* __restrict__ bbv,
    float* __restrict__ cA, float* __restrict__ cB)
{
    const int b = blockIdx.x;
    const float s0 = KSCALE*wa[0], s1 = KSCALE*wa[1];
    const float t0 = KSCALE*wb[0], t1 = KSCALE*wb[1];
    for (int hm = threadIdx.x; hm < KC2; hm += 256) {
        int h = hm >> 6, m = hm & 63;
        const float* kp = Kag + (size_t)(b*KNA + m)*KC2;
        const float* qp = Qa  + (size_t)(b*KNA + m)*KC2;
        float a = 0.f, bb2 = 0.f;
        for (int d = 0; d < KD; ++d) {
            a   += s0*bq_lf[h*KD+d]*kp[h*KD+d] + s1*bq_lf[KC+h*KD+d]*kp[KC+h*KD+d];
            bb2 += t0*bk_hf[h*KD+d]*qp[h*KD+d] + t1*bk_hf[KC+h*KD+d]*qp[KC+h*KD+d];
        }
        cA[(size_t)b*KC2 + hm] = a   + ba[0];
        cB[(size_t)b*KC2 + hm] = bb2 + bbv[0];
    }
}

// ---------------- k_vproj: V = attn @ Wv + bv -> Vt2 frag-major bf16 [b][n>>5][384][32]
__global__ __launch_bounds__(512, 4) void k_vproj(
    const unsigned short* __restrict__ Abf, const unsigned short* __restrict__ WvT2,
    const float* __restrict__ bv, unsigned short* __restrict__ Vt2)
{
    extern __shared__ char smem[];
    unsigned short* a_rm = (unsigned short*)smem;   // 49152B
    const int tid = threadIdx.x;
    const int wid = tid >> 6, lane = tid & 63;
    const int tx = lane & 15, ty = lane >> 4;
    const int nb = blockIdx.x, b = blockIdx.y;
    const int wn = wid >> 2, wd = wid & 3;

    const unsigned short* atile = Abf + ((size_t)b*KN + nb*64)*KC;
    #pragma unroll
    for (int i = 0; i < 6; ++i)
        gld_lds16(atile + (size_t)tid*8 + i*4096, a_rm + tid*8 + i*4096);

    f32x4 acc[2][6];
    #pragma unroll
    for (int i = 0; i < 2; ++i)
        #pragma unroll
        for (int j = 0; j < 6; ++j) acc[i][j] = (f32x4){0.f,0.f,0.f,0.f};
    __syncthreads();

    #pragma unroll
    for (int kk = 0; kk < 12; ++kk) {
        bf16x8 af[2];
        #pragma unroll
        for (int ns = 0; ns < 2; ++ns) {
            int n = wn*32 + ns*16 + tx;
            int gs = (kk*4 + ty) ^ (n & 7);
            af[ns] = *reinterpret_cast<const bf16x8*>(a_rm + n*384 + gs*8);
        }
        #pragma unroll
        for (int cs = 0; cs < 6; ++cs) {
            int d = wd*96 + cs*16 + tx;
            bf16x8 bf = *reinterpret_cast<const bf16x8*>(WvT2 + ((size_t)kk*KC + d)*32 + ty*8);
            #pragma unroll
            for (int ns = 0; ns < 2; ++ns)
                acc[ns][cs] = MFMA_16x16x32(af[ns], bf, acc[ns][cs], 0, 0, 0);
        }
    }
    // epilogue: + bv, write frag-major bf16
    #pragma unroll
    for (int cs = 0; cs < 6; ++cs) {
        int d = wd*96 + cs*16 + tx;
        float bvv = bv[d];
        #pragma unroll
        for (int ns = 0; ns < 2; ++ns) {
            ushort4 h4;
            h4.x = f2bf(acc[ns][cs][0] + bvv);
            h4.y = f2bf(acc[ns][cs][1] + bvv);
            h4.z = f2bf(acc[ns][cs][2] + bvv);
            h4.w = f2bf(acc[ns][cs][3] + bvv);
            size_t off = (((size_t)b*(KN>>5) + nb*2 + wn)*KC + d)*32 + ns*16 + ty*4;
            *reinterpret_cast<ushort4*>(Vt2 + off) = h4;
        }
    }
}

// ---------------- K3: V-form MFMA flash (branch B)
// LDS: a_rm 49152 + p [64][72] bf16 9216 + redl 512 = 58880 -> 2 blocks/CU
__global__ __launch_bounds__(512, 4) void k_flash3(
    const unsigned short* __restrict__ Abf, const unsigned short* __restrict__ Vt2,
    const unsigned short* __restrict__ Fbf, const float* __restrict__ cB,
    float* __restrict__ Vpart, float* __restrict__ lpart,
    int nchunk, int NK, int g_per)
{
    extern __shared__ char smem[];
    unsigned short* a_rm = (unsigned short*)smem;
    unsigned short* p    = (unsigned short*)(smem + 49152);
    float*          redl = (float*)(smem + 58368);

    const int tid = threadIdx.x;
    const int wid = tid >> 6, lane = tid & 63;
    const int tx = lane & 15, ty = lane >> 4;
    const unsigned bid = blockIdx.x;
    const int h = bid / g_per;
    const unsigned g = bid - h*g_per;
    const int b = g / nchunk;
    const int chunk = g - b*nchunk;
    const int n0 = chunk * NK;
    const int wn = wid >> 2, wh = wid & 3;   // QK^T roles
    const int wph = wid >> 1, wpd = wid & 1; // PV roles

    bf16x8 ffrag[12];
    {
        const unsigned short* fp = Fbf + ((size_t)(b*KC2 + h*64 + wh*16 + tx))*KC + ty*8;
        #pragma unroll
        for (int kk = 0; kk < 12; ++kk)
            ffrag[kk] = *reinterpret_cast<const bf16x8*>(fp + kk*32);
    }
    const float cbv = cB[(size_t)b*KC2 + h*64 + wh*16 + tx];
    float lacc = 0.f;
    f32x4 Vacc = (f32x4){0.f,0.f,0.f,0.f};

    const unsigned short* atile = Abf + ((size_t)b*KN + n0)*KC;
    #pragma unroll
    for (int i = 0; i < 6; ++i)
        gld_lds16(atile + (size_t)tid*8 + i*4096, a_rm + tid*8 + i*4096);
    __syncthreads();

    const int NT = NK >> 6;
    for (int nt = 0; nt < NT; ++nt) {
        // V B-frags for this tile (hidden under QK^T)
        size_t vrow = (size_t)b*(KN >> 5) + ((n0 + nt*64) >> 5);
        bf16x8 vf0 = *reinterpret_cast<const bf16x8*>(
            Vt2 + ((vrow + 0)*KC + h*KD + wpd*16 + tx)*32 + ty*8);
        bf16x8 vf1 = *reinterpret_cast<const bf16x8*>(
            Vt2 + ((vrow + 1)*KC + h*KD + wpd*16 + tx)*32 + ty*8);
        // QK^T: T'[n][hm]
        f32x4 tacc[2];
        tacc[0] = (f32x4){0.f,0.f,0.f,0.f};
        tacc[1] = (f32x4){0.f,0.f,0.f,0.f};
        #pragma unroll
        for (int kk = 0; kk < 12; ++kk) {
            #pragma unroll
            for (int ns = 0; ns < 2; ++ns) {
                int n = wn*32 + ns*16 + tx;
                int gs = (kk*4 + ty) ^ (n & 7);
                bf16x8 af = *reinterpret_cast<const bf16x8*>(a_rm + n*384 + gs*8);
                tacc[ns] = MFMA_16x16x32(af, ffrag[kk], tacc[ns], 0, 0, 0);
            }
        }
        // exp + lacc + pack P bf16 into p[hm][n]
        #pragma unroll
        for (int ns = 0; ns < 2; ++ns) {
            float e0 = __expf(tacc[ns][0] + cbv);
            float e1 = __expf(tacc[ns][1] + cbv);
            float e2 = __expf(tacc[ns][2] + cbv);
            float e3 = __expf(tacc[ns][3] + cbv);
            lacc += e0 + e1 + e2 + e3;
            int hm = wh*16 + tx;
            int np = wn*32 + ns*16 + ty*4;
            ushort4 h4 = { f2bf(e0), f2bf(e1), f2bf(e2), f2bf(e3) };
            *reinterpret_cast<ushort4*>(p + hm*72 + np) = h4;
        }
        __syncthreads();   // p visible; all QK^T reads of a_rm done
        if (nt + 1 < NT) {  // async stage next tile (overlaps PV)
            const unsigned short* at = atile + (size_t)(nt+1)*64*KC;
            #pragma unroll
            for (int i = 0; i < 6; ++i)
                gld_lds16(at + (size_t)tid*8 + i*4096, a_rm + tid*8 + i*4096);
        }
        // PV: Vacc += P_h @ V_h  (wave owns 16 hm x 16 d)
        bf16x8 pa0 = *reinterpret_cast<const bf16x8*>(p + (wph*16 + tx)*72 + 0*32 + ty*8);
        bf16x8 pa1 = *reinterpret_cast<const bf16x8*>(p + (wph*16 + tx)*72 + 1*32 + ty*8);
        Vacc = MFMA_16x16x32(pa0, vf0, Vacc, 0, 0, 0);
        Vacc = MFMA_16x16x32(pa1, vf1, Vacc, 0, 0, 0);
        __syncthreads();   // PV p-reads done + DMA landed
    }
    // epilogue: Vpart f32 [b][h][chunk][64 hm][32 d]
    #pragma unroll
    for (int r = 0; r < 4; ++r)
        Vpart[(((size_t)(b*KH + h)*nchunk + chunk)*64 + wph*16 + ty*4 + r)*32 + wpd*16 + tx]
            = Vacc[r];
    lacc += __shfl_xor(lacc, 16);
    lacc += __shfl_xor(lacc, 32);
    if (lane < 16) redl[wn*64 + wh*16 + tx] = lacc;
    __syncthreads();
    if (tid < 64)
        lpart[((size_t)b*KC2 + h*64 + tid)*nchunk + chunk] = redl[tid] + redl[64 + tid];
}

// ---------------- K4: combine2: x_s = (sum_ch Vpart)/l ; M = x_s @ Wproj_h
__global__ __launch_bounds__(128) void k_combine2(
    const float* __restrict__ Vpart, const float* __restrict__ lpart,
    const float* __restrict__ Wproj, float* __restrict__ M, int nchunk)
{
    __shared__ float red[4][32];
    __shared__ float xs[KD];
    const int hm = blockIdx.x, b = blockIdx.y;
    const int h = hm >> 6, hml = hm & 63;
    const int tid = threadIdx.x;
    float lsum = 0.f;
    for (int ch = 0; ch < nchunk; ++ch)
        lsum += lpart[(size_t)(b*KC2 + hm)*nchunk + ch];
    const float inv = 1.f / lsum;
    {
        const int q = tid >> 5, d = tid & 31;
        float u = 0.f;
        for (int ch = q; ch < nchunk; ch += 4)
            u += Vpart[(((size_t)(b*KH + h)*nchunk + ch)*64 + hml)*KD + d];
        red[q][d] = u;
    }
    __syncthreads();
    if (tid < KD) xs[tid] = (red[0][tid] + red[1][tid] + red[2][tid] + red[3][tid]) * inv;
    __syncthreads();
    #pragma unroll
    for (int l = 0; l < 3; ++l) {
        int e = tid + l*128;
        float acc = 0.f;
        #pragma unroll
        for (int d = 0; d < KD; ++d)
            acc = fmaf(xs[d], Wproj[(size_t)(h*KD + d)*KC + e], acc);
        M[((size_t)b*KC2 + hm)*KC + e] = acc;
    }
}

// ---------------- K5: MFMA out (branch A)
// LDS: xb [64][384] bf16 swz @0 (49152); p [64][72] @49152 (9216); red [64][4] f32 @58368 (1024)
__global__ __launch_bounds__(512, 4) void k_out2(
    const float* __restrict__ x, const unsigned short* __restrict__ Et2,
    const float* __restrict__ cA, const unsigned short* __restrict__ Mt2,
    const float* __restrict__ bproj, float* __restrict__ out)
{
    extern __shared__ char smem[];
    unsigned short* xb = (unsigned short*)smem;
    unsigned short* p  = (unsigned short*)(smem + 49152);
    float* red = (float*)(smem + 58368);

    const int tid = threadIdx.x;
    const int wid = tid >> 6, lane = tid & 63;
    const int tx = lane & 15, ty = lane >> 4;
    const int b = blockIdx.x, nb = blockIdx.y;   // b fastest -> per-XCD batch locality
    const int wn = wid >> 2, wm = wid & 3;
    const int un = wid >> 2, uc = wid & 3;

    f32x4 oacc[2][6];
    #pragma unroll
    for (int i = 0; i < 2; ++i)
        #pragma unroll
        for (int j = 0; j < 6; ++j) oacc[i][j] = (f32x4){0.f,0.f,0.f,0.f};

    {   // stage xb once (swizzled bf16 from f32 x)
        const float4* src = reinterpret_cast<const float4*>(x + ((size_t)(b*KN + nb*64))*KC);
        #pragma unroll
        for (int i = 0; i < 12; ++i) {
            int f = tid + i*512;
            int n = f / 96, c4 = f % 96;
            float4 v = src[f];
            ushort4 h4 = { f2bf(v.x), f2bf(v.y), f2bf(v.z), f2bf(v.w) };
            int g = c4 >> 1, half = c4 & 1;
            int gs = g ^ (n & 7);
            *reinterpret_cast<ushort4*>(xb + n*384 + gs*8 + half*4) = h4;
        }
    }
    // prologue prefetch: efrag(0), cav(0), mtpre ks0 (0)
    bf16x8 efrag[12];
    #pragma unroll
    for (int kk = 0; kk < 12; ++kk)
        efrag[kk] = *reinterpret_cast<const bf16x8*>(
            Et2 + (((size_t)b*12 + kk)*KC2 + wm*16 + tx)*32 + ty*8);
    float cav = cA[(size_t)b*KC2 + wm*16 + tx];
    bf16x8 mtpre[6];
    #pragma unroll
    for (int cs = 0; cs < 6; ++cs)
        mtpre[cs] = *reinterpret_cast<const bf16x8*>(
            Mt2 + (((size_t)(b*KH + 0)*2 + 0)*KC + uc*96 + cs*16 + tx)*32 + ty*8);
    __syncthreads();

    for (int hh = 0; hh < KH; ++hh) {
        // QK^T: L[n][m]
        f32x4 tacc[2];
        tacc[0] = (f32x4){0.f,0.f,0.f,0.f};
        tacc[1] = (f32x4){0.f,0.f,0.f,0.f};
        #pragma unroll
        for (int kk = 0; kk < 12; ++kk) {
            #pragma unroll
            for (int ns = 0; ns < 2; ++ns) {
                int n = wn*32 + ns*16 + tx;
                int gs = (kk*4 + ty) ^ (n & 7);
                bf16x8 af = *reinterpret_cast<const bf16x8*>(xb + n*384 + gs*8);
                tacc[ns] = MFMA_16x16x32(af, efrag[kk], tacc[ns], 0, 0, 0);
            }
        }
        // exp + row-sum over m (16-lane shuffle + cross-wave via red[n][4])
        float e[2][4], s[2][4];
        #pragma unroll
        for (int ns = 0; ns < 2; ++ns)
            #pragma unroll
            for (int r = 0; r < 4; ++r) {
                e[ns][r] = __expf(tacc[ns][r] + cav);
                s[ns][r] = e[ns][r];
            }
        #pragma unroll
        for (int mask = 1; mask < 16; mask <<= 1)
            #pragma unroll
            for (int ns = 0; ns < 2; ++ns)
                #pragma unroll
                for (int r = 0; r < 4; ++r)
                    s[ns][r] += __shfl_xor(s[ns][r], mask);
        if (tx == 0) {
            #pragma unroll
            for (int ns = 0; ns < 2; ++ns)
                #pragma unroll
                for (int r = 0; r < 4; ++r)
                    red[(wn*32 + ns*16 + ty*4 + r)*4 + wm] = s[ns][r];
        }
        __syncthreads();   // red visible; prev PV done -> p writable
        #pragma unroll
        for (int ns = 0; ns < 2; ++ns)
            #pragma unroll
            for (int r = 0; r < 4; ++r) {
                int n = wn*32 + ns*16 + ty*4 + r;
                float4 rv = *reinterpret_cast<const float4*>(red + n*4);
                float inv = 1.f / (rv.x + rv.y + rv.z + rv.w);
                p[n*72 + wm*16 + tx] = f2bf(e[ns][r] * inv);
            }
        __syncthreads();   // p visible
        // prefetch next head's E-frags + cA (hidden under PV)
        if (hh + 1 < KH) {
            #pragma unroll
            for (int kk = 0; kk < 12; ++kk)
                efrag[kk] = *reinterpret_cast<const bf16x8*>(
                    Et2 + (((size_t)b*12 + kk)*KC2 + (hh+1)*64 + wm*16 + tx)*32 + ty*8);
            cav = cA[(size_t)b*KC2 + (hh+1)*64 + wm*16 + tx];
        }
        // PV: oacc += P @ M^T ; ks0 from prefetched regs, ks1 inline
        {
            bf16x8 pa[2];
            #pragma unroll
            for (int ns = 0; ns < 2; ++ns)
                pa[ns] = *reinterpret_cast<const bf16x8*>(
                    p + (un*32 + ns*16 + tx)*72 + 0*32 + ty*8);
            #pragma unroll
            for (int cs = 0; cs < 6; ++cs)
                #pragma unroll
                for (int ns = 0; ns < 2; ++ns)
                    oacc[ns][cs] = MFMA_16x16x32(pa[ns], mtpre[cs], oacc[ns][cs], 0, 0, 0);
        }
        {
            bf16x8 pa[2];
            #pragma unroll
            for (int ns = 0; ns < 2; ++ns)
                pa[ns] = *reinterpret_cast<const bf16x8*>(
                    p + (un*32 + ns*16 + tx)*72 + 1*32 + ty*8);
            const unsigned short* mb = Mt2 + (((size_t)(b*KH + hh)*2 + 1)*KC)*32 + ty*8;
            #pragma unroll
            for (int cs = 0; cs < 6; ++cs) {
                int c = uc*96 + cs*16 + tx;
                bf16x8 bv2 = *reinterpret_cast<const bf16x8*>(mb + c*32);
                #pragma unroll
                for (int ns = 0; ns < 2; ++ns)
                    oacc[ns][cs] = MFMA_16x16x32(pa[ns], bv2, oacc[ns][cs], 0, 0, 0);
            }
        }
        // prefetch next head's Mt2 ks0 (hidden under next QK^T)
        if (hh + 1 < KH) {
            #pragma unroll
            for (int cs = 0; cs < 6; ++cs)
                mtpre[cs] = *reinterpret_cast<const bf16x8*>(
                    Mt2 + (((size_t)(b*KH + hh+1)*2 + 0)*KC + uc*96 + cs*16 + tx)*32 + ty*8);
        }
    }
    // epilogue
    float bp[6];
    #pragma unroll
    for (int cs = 0; cs < 6; ++cs) bp[cs] = bproj[uc*96 + cs*16 + tx];
    #pragma unroll
    for (int ns = 0; ns < 2; ++ns)
        #pragma unroll
        for (int r = 0; r < 4; ++r) {
            size_t base = (size_t)(b*KN + nb*64 + un*32 + ns*16 + ty*4 + r)*KC;
            #pragma unroll
            for (int cs = 0; cs < 6; ++cs)
                out[base + uc*96 + cs*16 + tx] = oacc[ns][cs][r] + bp[cs];
        }
}

extern "C" void kernel_launch(void* const* d_in, const int* in_sizes, int n_in,
                              void* d_out, int out_size, void* d_ws, size_t ws_size,
                              hipStream_t stream) {
    const float* x     = (const float*)d_in[0];
    const float* attn  = (const float*)d_in[1];
    const float* agent = (const float*)d_in[2];
    const float* Wq_lf = (const float*)d_in[3];
    const float* bq_lf = (const float*)d_in[4];
    const float* Wk_ag = (const float*)d_in[5];
    const float* bk_ag = (const float*)d_in[6];
    const float* wa    = (const float*)d_in[7];
    const float* ba    = (const float*)d_in[8];
    const float* Wq_ag = (const float*)d_in[9];
    const float* bq_ag = (const float*)d_in[10];
    const float* Wk_hf = (const float*)d_in[11];
    const float* bk_hf = (const float*)d_in[12];
    const float* Wv_hf = (const float*)d_in[13];
    const float* bv_hf = (const float*)d_in[14];
    const float* wb    = (const float*)d_in[15];
    const float* bb    = (const float*)d_in[16];
    const float* Wproj = (const float*)d_in[17];
    const float* bproj = (const float*)d_in[18];
    float* out = (float*)d_out;
    float* ws  = (float*)d_ws;

    // workspace layout (f32 units)
    const size_t o_Kag  = 0;          // 393216
    const size_t o_Qa   = 393216;     // 393216
    const size_t o_E    = 786432;     // 2359296
    const size_t o_cA   = 3145728;    // 6144
    const size_t o_cB   = 3151872;    // 6144
    const size_t o_Fbf  = 3158016;    // 1179648
    const size_t o_M    = 4337664;    // 2359296
    const size_t o_WkT  = 6696960;    // 294912
    const size_t o_Et2  = 6991872;    // 1179648
    const size_t o_Mt2  = 8171520;    // 1179648
    const size_t o_WvT2 = 9351168;    // 73728
    const size_t o_Abf  = 9424896;    // 3145728
    const size_t o_Vt2  = 12570624;   // 6291456
    const size_t o_lp_base = 18862080;

    int nchunk = 8;
    {
        const int cands[3] = {32, 16, 8};
        for (int ci = 0; ci < 3; ++ci) {
            size_t need = (o_lp_base + (size_t)202752 * cands[ci]) * 4ull;
            if (need <= ws_size) { nchunk = cands[ci]; break; }
        }
    }
    const size_t o_lp = o_lp_base;
    const size_t o_Vp = o_lp + (size_t)6144 * nchunk;

    unsigned short* Fbf  = (unsigned short*)(ws + o_Fbf);
    unsigned short* Et2  = (unsigned short*)(ws + o_Et2);
    unsigned short* Mt2  = (unsigned short*)(ws + o_Mt2);
    unsigned short* WvT2 = (unsigned short*)(ws + o_WvT2);
    unsigned short* Abf  = (unsigned short*)(ws + o_Abf);
    unsigned short* Vt2  = (unsigned short*)(ws + o_Vt2);

    k_agent_proj<<<dim3(64, 2), 256, 0, stream>>>(agent, Wk_ag, bk_ag, Wq_ag, bq_ag,
                                                  ws + o_Kag, ws + o_Qa);
    k_transpose<<<dim3(24, 12), dim3(32, 8), 0, stream>>>(Wk_hf, ws + o_WkT);
    k_build_E<<<dim3(48, 8), 256, 0, stream>>>(Wq_lf, ws + o_Kag, wa, ws + o_E);
    k_tcastT<<<dim3(6, 12, 8), 256, 0, stream>>>(ws + o_E, Et2, nullptr,
                                                 KC, KC2, (long)KC*KC2, (long)KC*KC2, 0);
    k_build_F<<<dim3(96, 8), 128, 0, stream>>>(ws + o_WkT, ws + o_Qa, wb, Fbf);
    k_build_c<<<8, 256, 0, stream>>>(bq_lf, ws + o_Kag, wa, ba, bk_hf, ws + o_Qa,
                                     wb, bb, ws + o_cA, ws + o_cB);
    // attn -> Abf (swizzled row-major bf16) only
    k_tcastT<<<dim3(64, 6, 8), 256, 0, stream>>>(attn, nullptr, Abf,
                                                 KN, KC, (long)KN*KC, 0, (long)KN*KC);
    // Wv [384][384] -> WvT2 frag-major  (384/64 = 6 row-tiles, 6 col-tiles)
    k_tcastT<<<dim3(6, 6, 1), 256, 0, stream>>>(Wv_hf, WvT2, nullptr,
                                                 KC, KC, 0, 0, 0);

    const int vp_lds = 49152;
    const int fl_lds = 58880;
    const int ko_lds = 59392;
    (void)hipFuncSetAttribute(reinterpret_cast<const void*>(k_vproj),
                              hipFuncAttributeMaxDynamicSharedMemorySize, vp_lds);
    (void)hipFuncSetAttribute(reinterpret_cast<const void*>(k_flash3),
                              hipFuncAttributeMaxDynamicSharedMemorySize, fl_lds);
    (void)hipFuncSetAttribute(reinterpret_cast<const void*>(k_out2),
                              hipFuncAttributeMaxDynamicSharedMemorySize, ko_lds);

    k_vproj<<<dim3(KN/64, KB), 512, vp_lds, stream>>>(Abf, WvT2, bv_hf, Vt2);

    const int g_per = KB * nchunk;
    k_flash3<<<dim3(KH * g_per), 512, fl_lds, stream>>>(
        Abf, Vt2, Fbf, ws + o_cB, ws + o_Vp, ws + o_lp, nchunk, KN / nchunk, g_per);
    k_combine2<<<dim3(KC2, KB), 128, 0, stream>>>(
        ws + o_Vp, ws + o_lp, Wproj, ws + o_M, nchunk);
    // M per (b,h) [64 m][384 c] -> Mt2 [2][384][32]
    k_tcastT<<<dim3(1, 6, 96), 256, 0, stream>>>(ws + o_M, Mt2, nullptr,
                                                 64, KC, (long)64*KC, (long)64*KC, 0);
    k_out2<<<dim3(KB, KN/64), 512, ko_lds, stream>>>(
        x, Et2, ws + o_cA, Mt2, bproj, out);
}

// Round 6
// 382.041 us; speedup vs baseline: 1.4402x; 1.4402x over previous
//
#include <hip/hip_runtime.h>

#define KB 8
#define KN 4096
#define KNA 64
#define KH 12
#define KD 32
#define KC 384
#define KC2 768
#define KSCALE 0.17677669529663688f

typedef __bf16 bf16x8 __attribute__((ext_vector_type(8)));
typedef float  f32x4  __attribute__((ext_vector_type(4)));

static __device__ __forceinline__ unsigned short f2bf(float f) {
    unsigned int u = __builtin_bit_cast(unsigned int, f);
    u += 0x7FFFu + ((u >> 16) & 1u);
    return (unsigned short)(u >> 16);
}

static __device__ __forceinline__ void gld_lds16(const unsigned short* g, unsigned short* l) {
    __builtin_amdgcn_global_load_lds(
        (const __attribute__((address_space(1))) unsigned int*)g,
        (__attribute__((address_space(3))) unsigned int*)l, 16, 0, 0);
}

#define MFMA_16x16x32 __builtin_amdgcn_mfma_f32_16x16x32_bf16

// ---------------- K0: Kag = agent@Wk_ag + bk ; Qa = agent@Wq_ag + bq
__global__ __launch_bounds__(256) void k_agent_proj(
    const float* __restrict__ agent,
    const float* __restrict__ Wk_ag, const float* __restrict__ bk_ag,
    const float* __restrict__ Wq_ag, const float* __restrict__ bq_ag,
    float* __restrict__ Kag, float* __restrict__ Qa)
{
    __shared__ float a_lds[8][KC];
    const int tid = threadIdx.x;
    const int rg  = blockIdx.x;
    const float* W    = blockIdx.y ? Wq_ag : Wk_ag;
    const float* bias = blockIdx.y ? bq_ag : bk_ag;
    float* dst        = blockIdx.y ? Qa    : Kag;

    const float4* src4 = reinterpret_cast<const float4*>(agent) + (size_t)rg * 768;
    float4* al4 = reinterpret_cast<float4*>(&a_lds[0][0]);
    #pragma unroll
    for (int l = 0; l < 3; ++l) al4[tid + l*256] = src4[tid + l*256];
    __syncthreads();

    float acc[8][3] = {};
    for (int c = 0; c < KC; ++c) {
        float w0 = W[(size_t)c*KC2 + tid];
        float w1 = W[(size_t)c*KC2 + tid + 256];
        float w2 = W[(size_t)c*KC2 + tid + 512];
        #pragma unroll
        for (int r = 0; r < 8; ++r) {
            float a = a_lds[r][c];
            acc[r][0] = fmaf(a, w0, acc[r][0]);
            acc[r][1] = fmaf(a, w1, acc[r][1]);
            acc[r][2] = fmaf(a, w2, acc[r][2]);
        }
    }
    float b0 = bias[tid], b1 = bias[tid+256], b2 = bias[tid+512];
    #pragma unroll
    for (int r = 0; r < 8; ++r) {
        size_t base = (size_t)(rg*8 + r) * KC2;
        dst[base + tid      ] = acc[r][0] + b0;
        dst[base + tid + 256] = acc[r][1] + b1;
        dst[base + tid + 512] = acc[r][2] + b2;
    }
}

// ---------------- transpose Wk_hf [384,768] -> WkT [768,384] (f32)
__global__ __launch_bounds__(256) void k_transpose(
    const float* __restrict__ Win, float* __restrict__ Wout)
{
    __shared__ float tile[32][33];
    const int tx = threadIdx.x, ty = threadIdx.y;
    const int j0 = blockIdx.x * 32, c0 = blockIdx.y * 32;
    #pragma unroll
    for (int yy = 0; yy < 4; ++yy)
        tile[ty + yy*8][tx] = Win[(size_t)(c0 + ty + yy*8)*KC2 + j0 + tx];
    __syncthreads();
    #pragma unroll
    for (int yy = 0; yy < 4; ++yy)
        Wout[(size_t)(j0 + ty + yy*8)*KC + c0 + tx] = tile[tx][ty + yy*8];
}

// ---------------- tcastT: src f32 [R][C] -> dstT bf16 frag-major [(r>>5)][C][32]
//                  optional dstRM: bf16 row-major, 16B-granule XOR-swizzled (g^(r&7))
__global__ __launch_bounds__(256) void k_tcastT(
    const float* __restrict__ src, unsigned short* __restrict__ dstT,
    unsigned short* __restrict__ dstRM,
    int R, int C, long sstride, long dTstride, long dRMstride)
{
    __shared__ unsigned short lds[64][80];
    const int t = threadIdx.x;
    const int r0 = blockIdx.x * 64, c0 = blockIdx.y * 64;
    const float* s = src + (size_t)blockIdx.z * sstride;
    #pragma unroll
    for (int i = 0; i < 16; ++i) {
        int f = t + i*256; int rr = f >> 6, cc = f & 63;
        lds[rr][cc] = f2bf(s[(size_t)(r0+rr)*C + c0 + cc]);
    }
    __syncthreads();
    if (dstT) {
        unsigned short* dT = dstT + (size_t)blockIdx.z * dTstride;
        #pragma unroll
        for (int i = 0; i < 8; ++i) {
            int o = t + i*256;
            int chunk = o >> 10, c = (o >> 4) & 63, pair = o & 15;
            int r = chunk*32 + pair*2;
            unsigned int v = (unsigned int)lds[r][c] | ((unsigned int)lds[r+1][c] << 16);
            size_t off = ((size_t)((r0>>5) + chunk)*C + c0 + c)*32 + pair*2;
            *reinterpret_cast<unsigned int*>(dT + off) = v;
        }
    }
    if (dstRM) {
        unsigned short* dR = dstRM + (size_t)blockIdx.z * dRMstride;
        #pragma unroll
        for (int i = 0; i < 2; ++i) {
            int idx = t*2 + i;
            int n = idx >> 3, gt = idx & 7;
            int g = (c0 >> 3) + gt;
            int slot = g ^ ((r0 + n) & 7);
            *reinterpret_cast<bf16x8*>(dR + (size_t)(r0+n)*C + slot*8) =
                *reinterpret_cast<const bf16x8*>(&lds[n][gt*8]);
        }
    }
}

// ---------------- K1: E[b][c][hm]  (f32)
__global__ __launch_bounds__(256) void k_build_E(
    const float* __restrict__ Wq_lf, const float* __restrict__ Kag,
    const float* __restrict__ wa, float* __restrict__ E)
{
    __shared__ float w_lds[8][KC2];
    const int tid = threadIdx.x;
    const int cg = blockIdx.x;
    const int b  = blockIdx.y;
    const float4* src = reinterpret_cast<const float4*>(Wq_lf + (size_t)cg*8*KC2);
    float4* dst4 = reinterpret_cast<float4*>(&w_lds[0][0]);
    #pragma unroll
    for (int l = 0; l < 6; ++l) dst4[tid + l*256] = src[tid + l*256];
    __syncthreads();
    const float s0 = KSCALE * wa[0], s1 = KSCALE * wa[1];
    float acc[8][3] = {};
    #pragma unroll
    for (int j = 0; j < 3; ++j) {
        const int hm = tid + j*256;
        const int h = hm >> 6, m = hm & 63;
        const float* kp = Kag + (size_t)(b*KNA + m)*KC2;
        const int base1 = h*KD, base2 = KC + h*KD;
        for (int d = 0; d < KD; ++d) {
            float a1 = kp[base1 + d] * s0;
            float a2 = kp[base2 + d] * s1;
            #pragma unroll
            for (int cr = 0; cr < 8; ++cr)
                acc[cr][j] += w_lds[cr][base1+d]*a1 + w_lds[cr][base2+d]*a2;
        }
    }
    #pragma unroll
    for (int cr = 0; cr < 8; ++cr)
        #pragma unroll
        for (int j = 0; j < 3; ++j)
            E[((size_t)b*KC + cg*8 + cr)*KC2 + tid + j*256] = acc[cr][j];
}

// ---------------- K2b: F_bf[b][hm][c] bf16 row-major
__global__ __launch_bounds__(128) void k_build_F(
    const float* __restrict__ WkT, const float* __restrict__ Qa,
    const float* __restrict__ wb, unsigned short* __restrict__ Fbf)
{
    __shared__ float q_lds[8][64];
    const int tid = threadIdx.x;
    const int g = blockIdx.x;
    const int b = blockIdx.y;
    const int h = (g*8) >> 6;
    const float t0 = KSCALE*wb[0], t1 = KSCALE*wb[1];
    #pragma unroll
    for (int l = 0; l < 4; ++l) {
        int v = tid + l*128;
        int i = v >> 6, d = v & 63;
        int m = (g*8 + i) & 63;
        int jj   = (d < KD) ? (h*KD + d) : (KC + h*KD + d - KD);
        float cf = (d < KD) ? t0 : t1;
        q_lds[i][d] = cf * Qa[(size_t)(b*KNA + m)*KC2 + jj];
    }
    __syncthreads();
    float acc[8][3] = {};
    for (int d = 0; d < 64; ++d) {
        int row = (d < KD) ? (h*KD + d) : (KC + h*KD + d - KD);
        const float* wr = WkT + (size_t)row*KC;
        float w0 = wr[tid], w1 = wr[tid+128], w2 = wr[tid+256];
        #pragma unroll
        for (int i = 0; i < 8; ++i) {
            float q = q_lds[i][d];
            acc[i][0] = fmaf(q, w0, acc[i][0]);
            acc[i][1] = fmaf(q, w1, acc[i][1]);
            acc[i][2] = fmaf(q, w2, acc[i][2]);
        }
    }
    #pragma unroll
    for (int i = 0; i < 8; ++i)
        #pragma unroll
        for (int l = 0; l < 3; ++l)
            Fbf[((size_t)b*KC2 + g*8 + i)*KC + tid + l*128] = f2bf(acc[i][l]);
}

// ---------------- K1c: bias constants cA, cB
__global__ __launch_bounds__(256) void k_build_c(
    const float* __restrict__ bq_lf, const float* __restrict__ Kag,
    const float* __restrict__ wa, const float* __restrict__ ba,
    const float* __restrict__ bk_hf, const float* __restrict__ Qa,
    const float* __restrict__ wb, const float* __restrict__ bbv,
    float* __restrict__ cA, float* __restrict__ cB)
{
    const int b = blockIdx.x;
    const float s0 = KSCALE*wa[0], s1 = KSCALE*wa[1];
    const float t0 = KSCALE*wb[0], t1 = KSCALE*wb[1];
    for (int hm = threadIdx.x; hm < KC2; hm += 256) {
        int h = hm >> 6, m = hm & 63;
        const float* kp = Kag + (size_t)(b*KNA + m)*KC2;
        const float* qp = Qa  + (size_t)(b*KNA + m)*KC2;
        float a = 0.f, bb2 = 0.f;
        for (int d = 0; d < KD; ++d) {
            a   += s0*bq_lf[h*KD+d]*kp[h*KD+d] + s1*bq_lf[KC+h*KD+d]*kp[KC+h*KD+d];
            bb2 += t0*bk_hf[h*KD+d]*qp[h*KD+d] + t1*bk_hf[KC+h*KD+d]*qp[KC+h*KD+d];
        }
        cA[(size_t)b*KC2 + hm] = a   + ba[0];
        cB[(size_t)b*KC2 + hm] = bb2 + bbv[0];
    }
}

// ---------------- k_vproj: V = attn @ Wv + bv -> Vt2 frag-major bf16 [b][n>>5][384][32]
__global__ __launch_bounds__(512, 4) void k_vproj(
    const unsigned short* __restrict__ Abf, const unsigned short* __restrict__ WvT2,
    const float* __restrict__ bv, unsigned short* __restrict__ Vt2)
{
    extern __shared__ char smem[];
    unsigned short* a_rm = (unsigned short*)smem;   // 49152B
    const int tid = threadIdx.x;
    const int wid = tid >> 6, lane = tid & 63;
    const int tx = lane & 15, ty = lane >> 4;
    const int nb = blockIdx.x, b = blockIdx.y;
    const int wn = wid >> 2, wd = wid & 3;

    const unsigned short* atile = Abf + ((size_t)b*KN + nb*64)*KC;
    #pragma unroll
    for (int i = 0; i < 6; ++i)
        gld_lds16(atile + (size_t)tid*8 + i*4096, a_rm + tid*8 + i*4096);

    f32x4 acc[2][6];
    #pragma unroll
    for (int i = 0; i < 2; ++i)
        #pragma unroll
        for (int j = 0; j < 6; ++j) acc[i][j] = (f32x4){0.f,0.f,0.f,0.f};
    __syncthreads();

    #pragma unroll
    for (int kk = 0; kk < 12; ++kk) {
        bf16x8 af[2];
        #pragma unroll
        for (int ns = 0; ns < 2; ++ns) {
            int n = wn*32 + ns*16 + tx;
            int gs = (kk*4 + ty) ^ (n & 7);
            af[ns] = *reinterpret_cast<const bf16x8*>(a_rm + n*384 + gs*8);
        }
        #pragma unroll
        for (int cs = 0; cs < 6; ++cs) {
            int d = wd*96 + cs*16 + tx;
            bf16x8 bf = *reinterpret_cast<const bf16x8*>(WvT2 + ((size_t)kk*KC + d)*32 + ty*8);
            #pragma unroll
            for (int ns = 0; ns < 2; ++ns)
                acc[ns][cs] = MFMA_16x16x32(af[ns], bf, acc[ns][cs], 0, 0, 0);
        }
    }
    // epilogue: + bv, write frag-major bf16
    #pragma unroll
    for (int cs = 0; cs < 6; ++cs) {
        int d = wd*96 + cs*16 + tx;
        float bvv = bv[d];
        #pragma unroll
        for (int ns = 0; ns < 2; ++ns) {
            ushort4 h4;
            h4.x = f2bf(acc[ns][cs][0] + bvv);
            h4.y = f2bf(acc[ns][cs][1] + bvv);
            h4.z = f2bf(acc[ns][cs][2] + bvv);
            h4.w = f2bf(acc[ns][cs][3] + bvv);
            size_t off = (((size_t)b*(KN>>5) + nb*2 + wn)*KC + d)*32 + ns*16 + ty*4;
            *reinterpret_cast<ushort4*>(Vt2 + off) = h4;
        }
    }
}

// ---------------- K3: V-form MFMA flash (branch B)
// LDS: a_rm 49152 + p [64][72] bf16 9216 + redl 512 = 58880 -> 2 blocks/CU
__global__ __launch_bounds__(512, 4) void k_flash3(
    const unsigned short* __restrict__ Abf, const unsigned short* __restrict__ Vt2,
    const unsigned short* __restrict__ Fbf, const float* __restrict__ cB,
    float* __restrict__ Vpart, float* __restrict__ lpart,
    int nchunk, int NK, int g_per)
{
    extern __shared__ char smem[];
    unsigned short* a_rm = (unsigned short*)smem;
    unsigned short* p    = (unsigned short*)(smem + 49152);
    float*          redl = (float*)(smem + 58368);

    const int tid = threadIdx.x;
    const int wid = tid >> 6, lane = tid & 63;
    const int tx = lane & 15, ty = lane >> 4;
    const unsigned bid = blockIdx.x;
    const int h = bid / g_per;
    const unsigned g = bid - h*g_per;
    const int b = g / nchunk;
    const int chunk = g - b*nchunk;
    const int n0 = chunk * NK;
    const int wn = wid >> 2, wh = wid & 3;   // QK^T roles
    const int wph = wid >> 1, wpd = wid & 1; // PV roles

    bf16x8 ffrag[12];
    {
        const unsigned short* fp = Fbf + ((size_t)(b*KC2 + h*64 + wh*16 + tx))*KC + ty*8;
        #pragma unroll
        for (int kk = 0; kk < 12; ++kk)
            ffrag[kk] = *reinterpret_cast<const bf16x8*>(fp + kk*32);
    }
    const float cbv = cB[(size_t)b*KC2 + h*64 + wh*16 + tx];
    float lacc = 0.f;
    f32x4 Vacc = (f32x4){0.f,0.f,0.f,0.f};

    const unsigned short* atile = Abf + ((size_t)b*KN + n0)*KC;
    #pragma unroll
    for (int i = 0; i < 6; ++i)
        gld_lds16(atile + (size_t)tid*8 + i*4096, a_rm + tid*8 + i*4096);
    __syncthreads();

    const int NT = NK >> 6;
    for (int nt = 0; nt < NT; ++nt) {
        // V B-frags for this tile (hidden under QK^T)
        size_t vrow = (size_t)b*(KN >> 5) + ((n0 + nt*64) >> 5);
        bf16x8 vf0 = *reinterpret_cast<const bf16x8*>(
            Vt2 + ((vrow + 0)*KC + h*KD + wpd*16 + tx)*32 + ty*8);
        bf16x8 vf1 = *reinterpret_cast<const bf16x8*>(
            Vt2 + ((vrow + 1)*KC + h*KD + wpd*16 + tx)*32 + ty*8);
        // QK^T: T'[n][hm]
        f32x4 tacc[2];
        tacc[0] = (f32x4){0.f,0.f,0.f,0.f};
        tacc[1] = (f32x4){0.f,0.f,0.f,0.f};
        __builtin_amdgcn_s_setprio(1);
        #pragma unroll
        for (int kk = 0; kk < 12; ++kk) {
            #pragma unroll
            for (int ns = 0; ns < 2; ++ns) {
                int n = wn*32 + ns*16 + tx;
                int gs = (kk*4 + ty) ^ (n & 7);
                bf16x8 af = *reinterpret_cast<const bf16x8*>(a_rm + n*384 + gs*8);
                tacc[ns] = MFMA_16x16x32(af, ffrag[kk], tacc[ns], 0, 0, 0);
            }
        }
        __builtin_amdgcn_s_setprio(0);
        // exp + lacc + pack P bf16 into p[hm][n]
        #pragma unroll
        for (int ns = 0; ns < 2; ++ns) {
            float e0 = __expf(tacc[ns][0] + cbv);
            float e1 = __expf(tacc[ns][1] + cbv);
            float e2 = __expf(tacc[ns][2] + cbv);
            float e3 = __expf(tacc[ns][3] + cbv);
            lacc += e0 + e1 + e2 + e3;
            int hm = wh*16 + tx;
            int np = wn*32 + ns*16 + ty*4;
            ushort4 h4 = { f2bf(e0), f2bf(e1), f2bf(e2), f2bf(e3) };
            *reinterpret_cast<ushort4*>(p + hm*72 + np) = h4;
        }
        __syncthreads();   // p visible; all QK^T reads of a_rm done
        if (nt + 1 < NT) {  // async stage next tile (overlaps PV)
            const unsigned short* at = atile + (size_t)(nt+1)*64*KC;
            #pragma unroll
            for (int i = 0; i < 6; ++i)
                gld_lds16(at + (size_t)tid*8 + i*4096, a_rm + tid*8 + i*4096);
        }
        // PV: Vacc += P_h @ V_h  (wave owns 16 hm x 16 d)
        bf16x8 pa0 = *reinterpret_cast<const bf16x8*>(p + (wph*16 + tx)*72 + 0*32 + ty*8);
        bf16x8 pa1 = *reinterpret_cast<const bf16x8*>(p + (wph*16 + tx)*72 + 1*32 + ty*8);
        Vacc = MFMA_16x16x32(pa0, vf0, Vacc, 0, 0, 0);
        Vacc = MFMA_16x16x32(pa1, vf1, Vacc, 0, 0, 0);
        __syncthreads();   // PV p-reads done + DMA landed
    }
    // epilogue: Vpart f32 [b][h][chunk][64 hm][32 d]
    #pragma unroll
    for (int r = 0; r < 4; ++r)
        Vpart[(((size_t)(b*KH + h)*nchunk + chunk)*64 + wph*16 + ty*4 + r)*32 + wpd*16 + tx]
            = Vacc[r];
    lacc += __shfl_xor(lacc, 16);
    lacc += __shfl_xor(lacc, 32);
    if (lane < 16) redl[wn*64 + wh*16 + tx] = lacc;
    __syncthreads();
    if (tid < 64)
        lpart[((size_t)b*KC2 + h*64 + tid)*nchunk + chunk] = redl[tid] + redl[64 + tid];
}

// ---------------- K4: combine2: x_s = (sum_ch Vpart)/l ; M = x_s @ Wproj_h
__global__ __launch_bounds__(128) void k_combine2(
    const float* __restrict__ Vpart, const float* __restrict__ lpart,
    const float* __restrict__ Wproj, float* __restrict__ M, int nchunk)
{
    __shared__ float red[4][32];
    __shared__ float xs[KD];
    const int hm = blockIdx.x, b = blockIdx.y;
    const int h = hm >> 6, hml = hm & 63;
    const int tid = threadIdx.x;
    float lsum = 0.f;
    for (int ch = 0; ch < nchunk; ++ch)
        lsum += lpart[(size_t)(b*KC2 + hm)*nchunk + ch];
    const float inv = 1.f / lsum;
    {
        const int q = tid >> 5, d = tid & 31;
        float u = 0.f;
        for (int ch = q; ch < nchunk; ch += 4)
            u += Vpart[(((size_t)(b*KH + h)*nchunk + ch)*64 + hml)*KD + d];
        red[q][d] = u;
    }
    __syncthreads();
    if (tid < KD) xs[tid] = (red[0][tid] + red[1][tid] + red[2][tid] + red[3][tid]) * inv;
    __syncthreads();
    #pragma unroll
    for (int l = 0; l < 3; ++l) {
        int e = tid + l*128;
        float acc = 0.f;
        #pragma unroll
        for (int d = 0; d < KD; ++d)
            acc = fmaf(xs[d], Wproj[(size_t)(h*KD + d)*KC + e], acc);
        M[((size_t)b*KC2 + hm)*KC + e] = acc;
    }
}

// ---------------- K5: MFMA out v3 (branch A): 2 heads/iter, wave-owns-full-n
// LDS: xb [64][384] bf16 swz @0 (49152); p [64][140] bf16 @49152 (17920);
//      red [2][64][4] f32 @67072 (2048); total 69120 -> 2 blocks/CU
__global__ __launch_bounds__(512, 4) void k_out3(
    const float* __restrict__ x, const unsigned short* __restrict__ Et2,
    const float* __restrict__ cA, const unsigned short* __restrict__ Mt2,
    const float* __restrict__ bproj, float* __restrict__ out)
{
    extern __shared__ char smem[];
    unsigned short* xb = (unsigned short*)smem;
    unsigned short* p  = (unsigned short*)(smem + 49152);   // pitch 140
    float* red = (float*)(smem + 67072);                    // [2][64][4]

    const int tid = threadIdx.x;
    const int wid = tid >> 6, lane = tid & 63;
    const int tx = lane & 15, ty = lane >> 4;
    const int nb = blockIdx.x, b = blockIdx.y;
    const int hq2 = wid >> 2, wm = wid & 3;   // QK^T: head-of-pair, m-slice
    const int es = wid * 48;                  // PV: e-slice

    f32x4 oacc[4][3];
    #pragma unroll
    for (int i = 0; i < 4; ++i)
        #pragma unroll
        for (int j = 0; j < 3; ++j) oacc[i][j] = (f32x4){0.f,0.f,0.f,0.f};

    {   // stage xb once (swizzled bf16 from f32 x)
        const float4* src = reinterpret_cast<const float4*>(x + ((size_t)(b*KN + nb*64))*KC);
        #pragma unroll
        for (int i = 0; i < 12; ++i) {
            int f = tid + i*512;
            int n = f / 96, c4 = f % 96;
            float4 v = src[f];
            ushort4 h4 = { f2bf(v.x), f2bf(v.y), f2bf(v.z), f2bf(v.w) };
            int g = c4 >> 1, half = c4 & 1;
            int gs = g ^ (n & 7);
            *reinterpret_cast<ushort4*>(xb + n*384 + gs*8 + half*4) = h4;
        }
    }
    __syncthreads();

    for (int it = 0; it < 6; ++it) {
        const int hq = it*2 + hq2;
        const float cav = cA[(size_t)b*KC2 + hq*64 + wm*16 + tx];
        // ---- QK^T: wave computes [64 n][16 m] for head hq, m-slice wm
        f32x4 tacc[4];
        #pragma unroll
        for (int ng = 0; ng < 4; ++ng) tacc[ng] = (f32x4){0.f,0.f,0.f,0.f};
        __builtin_amdgcn_s_setprio(1);
        #pragma unroll
        for (int kk = 0; kk < 12; ++kk) {
            bf16x8 ef = *reinterpret_cast<const bf16x8*>(
                Et2 + (((size_t)b*12 + kk)*KC2 + hq*64 + wm*16 + tx)*32 + ty*8);
            #pragma unroll
            for (int ng = 0; ng < 4; ++ng) {
                int n = ng*16 + tx;
                int gs = (kk*4 + ty) ^ (n & 7);
                bf16x8 af = *reinterpret_cast<const bf16x8*>(xb + n*384 + gs*8);
                tacc[ng] = MFMA_16x16x32(af, ef, tacc[ng], 0, 0, 0);
            }
        }
        __builtin_amdgcn_s_setprio(0);
        // ---- exp + partial row-sum over this wave's 16 m (shuffle within 16 lanes)
        float s[4][4];
        #pragma unroll
        for (int ng = 0; ng < 4; ++ng)
            #pragma unroll
            for (int r = 0; r < 4; ++r) {
                tacc[ng][r] = __expf(tacc[ng][r] + cav);
                s[ng][r] = tacc[ng][r];
            }
        #pragma unroll
        for (int mask = 1; mask < 16; mask <<= 1)
            #pragma unroll
            for (int ng = 0; ng < 4; ++ng)
                #pragma unroll
                for (int r = 0; r < 4; ++r)
                    s[ng][r] += __shfl_xor(s[ng][r], mask);
        if (tx == 0) {
            #pragma unroll
            for (int ng = 0; ng < 4; ++ng)
                #pragma unroll
                for (int r = 0; r < 4; ++r)
                    red[(hq2*64 + ng*16 + ty*4 + r)*4 + wm] = s[ng][r];
        }
        __syncthreads();   // red visible; prev PV p-reads done
        // ---- normalize + write P bf16 into p[n][hq2*64 + wm*16 + tx]
        #pragma unroll
        for (int ng = 0; ng < 4; ++ng)
            #pragma unroll
            for (int r = 0; r < 4; ++r) {
                int n = ng*16 + ty*4 + r;
                float4 rv = *reinterpret_cast<const float4*>(red + (hq2*64 + n)*4);
                float inv = 1.f / (rv.x + rv.y + rv.z + rv.w);
                p[n*140 + hq2*64 + wm*16 + tx] = f2bf(tacc[ng][r] * inv);
            }
        __syncthreads();   // p visible
        // ---- PV: oacc += P[64 n][128 k] @ M2[128 k][48 e-slice]
        __builtin_amdgcn_s_setprio(1);
        #pragma unroll
        for (int ks = 0; ks < 4; ++ks) {
            const int hM = it*2 + (ks >> 1);
            const int inner = ks & 1;
            bf16x8 pa[4];
            #pragma unroll
            for (int ng = 0; ng < 4; ++ng)
                pa[ng] = *reinterpret_cast<const bf16x8*>(
                    p + (ng*16 + tx)*140 + ks*32 + ty*8);
            #pragma unroll
            for (int j = 0; j < 3; ++j) {
                bf16x8 mf = *reinterpret_cast<const bf16x8*>(
                    Mt2 + (((size_t)(b*KH + hM)*2 + inner)*KC + es + j*16 + tx)*32 + ty*8);
                #pragma unroll
                for (int ng = 0; ng < 4; ++ng)
                    oacc[ng][j] = MFMA_16x16x32(pa[ng], mf, oacc[ng][j], 0, 0, 0);
            }
        }
        __builtin_amdgcn_s_setprio(0);
    }
    // epilogue
    float bp[3];
    #pragma unroll
    for (int j = 0; j < 3; ++j) bp[j] = bproj[es + j*16 + tx];
    #pragma unroll
    for (int ng = 0; ng < 4; ++ng)
        #pragma unroll
        for (int r = 0; r < 4; ++r) {
            size_t base = (size_t)(b*KN + nb*64 + ng*16 + ty*4 + r)*KC;
            #pragma unroll
            for (int j = 0; j < 3; ++j)
                out[base + es + j*16 + tx] = oacc[ng][j][r] + bp[j];
        }
}

extern "C" void kernel_launch(void* const* d_in, const int* in_sizes, int n_in,
                              void* d_out, int out_size, void* d_ws, size_t ws_size,
                              hipStream_t stream) {
    const float* x     = (const float*)d_in[0];
    const float* attn  = (const float*)d_in[1];
    const float* agent = (const float*)d_in[2];
    const float* Wq_lf = (const float*)d_in[3];
    const float* bq_lf = (const float*)d_in[4];
    const float* Wk_ag = (const float*)d_in[5];
    const float* bk_ag = (const float*)d_in[6];
    const float* wa    = (const float*)d_in[7];
    const float* ba    = (const float*)d_in[8];
    const float* Wq_ag = (const float*)d_in[9];
    const float* bq_ag = (const float*)d_in[10];
    const float* Wk_hf = (const float*)d_in[11];
    const float* bk_hf = (const float*)d_in[12];
    const float* Wv_hf = (const float*)d_in[13];
    const float* bv_hf = (const float*)d_in[14];
    const float* wb    = (const float*)d_in[15];
    const float* bb    = (const float*)d_in[16];
    const float* Wproj = (const float*)d_in[17];
    const float* bproj = (const float*)d_in[18];
    float* out = (float*)d_out;
    float* ws  = (float*)d_ws;

    // workspace layout (f32 units)
    const size_t o_Kag  = 0;          // 393216
    const size_t o_Qa   = 393216;     // 393216
    const size_t o_E    = 786432;     // 2359296
    const size_t o_cA   = 3145728;    // 6144
    const size_t o_cB   = 3151872;    // 6144
    const size_t o_Fbf  = 3158016;    // 1179648
    const size_t o_M    = 4337664;    // 2359296
    const size_t o_WkT  = 6696960;    // 294912
    const size_t o_Et2  = 6991872;    // 1179648
    const size_t o_Mt2  = 8171520;    // 1179648
    const size_t o_WvT2 = 9351168;    // 73728
    const size_t o_Abf  = 9424896;    // 3145728
    const size_t o_Vt2  = 12570624;   // 6291456
    const size_t o_lp_base = 18862080;

    int nchunk = 8;
    {
        const int cands[3] = {32, 16, 8};
        for (int ci = 0; ci < 3; ++ci) {
            size_t need = (o_lp_base + (size_t)202752 * cands[ci]) * 4ull;
            if (need <= ws_size) { nchunk = cands[ci]; break; }
        }
    }
    const size_t o_lp = o_lp_base;
    const size_t o_Vp = o_lp + (size_t)6144 * nchunk;

    unsigned short* Fbf  = (unsigned short*)(ws + o_Fbf);
    unsigned short* Et2  = (unsigned short*)(ws + o_Et2);
    unsigned short* Mt2  = (unsigned short*)(ws + o_Mt2);
    unsigned short* WvT2 = (unsigned short*)(ws + o_WvT2);
    unsigned short* Abf  = (unsigned short*)(ws + o_Abf);
    unsigned short* Vt2  = (unsigned short*)(ws + o_Vt2);

    k_agent_proj<<<dim3(64, 2), 256, 0, stream>>>(agent, Wk_ag, bk_ag, Wq_ag, bq_ag,
                                                  ws + o_Kag, ws + o_Qa);
    k_transpose<<<dim3(24, 12), dim3(32, 8), 0, stream>>>(Wk_hf, ws + o_WkT);
    k_build_E<<<dim3(48, 8), 256, 0, stream>>>(Wq_lf, ws + o_Kag, wa, ws + o_E);
    k_tcastT<<<dim3(6, 12, 8), 256, 0, stream>>>(ws + o_E, Et2, nullptr,
                                                 KC, KC2, (long)KC*KC2, (long)KC*KC2, 0);
    k_build_F<<<dim3(96, 8), 128, 0, stream>>>(ws + o_WkT, ws + o_Qa, wb, Fbf);
    k_build_c<<<8, 256, 0, stream>>>(bq_lf, ws + o_Kag, wa, ba, bk_hf, ws + o_Qa,
                                     wb, bb, ws + o_cA, ws + o_cB);
    // attn -> Abf (swizzled row-major bf16) only
    k_tcastT<<<dim3(64, 6, 8), 256, 0, stream>>>(attn, nullptr, Abf,
                                                 KN, KC, (long)KN*KC, 0, (long)KN*KC);
    // Wv [384][384] -> WvT2 frag-major  (6 row-tiles, 6 col-tiles)
    k_tcastT<<<dim3(6, 6, 1), 256, 0, stream>>>(Wv_hf, WvT2, nullptr,
                                                 KC, KC, 0, 0, 0);

    const int vp_lds = 49152;
    const int fl_lds = 58880;
    const int ko_lds = 69120;
    (void)hipFuncSetAttribute(reinterpret_cast<const void*>(k_vproj),
                              hipFuncAttributeMaxDynamicSharedMemorySize, vp_lds);
    (void)hipFuncSetAttribute(reinterpret_cast<const void*>(k_flash3),
                              hipFuncAttributeMaxDynamicSharedMemorySize, fl_lds);
    (void)hipFuncSetAttribute(reinterpret_cast<const void*>(k_out3),
                              hipFuncAttributeMaxDynamicSharedMemorySize, ko_lds);

    k_vproj<<<dim3(KN/64, KB), 512, vp_lds, stream>>>(Abf, WvT2, bv_hf, Vt2);

    const int g_per = KB * nchunk;
    k_flash3<<<dim3(KH * g_per), 512, fl_lds, stream>>>(
        Abf, Vt2, Fbf, ws + o_cB, ws + o_Vp, ws + o_lp, nchunk, KN / nchunk, g_per);
    k_combine2<<<dim3(KC2, KB), 128, 0, stream>>>(
        ws + o_Vp, ws + o_lp, Wproj, ws + o_M, nchunk);
    // M per (b,h) [64 m][384 c] -> Mt2 [2][384][32]
    k_tcastT<<<dim3(1, 6, 96), 256, 0, stream>>>(ws + o_M, Mt2, nullptr,
                                                 64, KC, (long)64*KC, (long)64*KC, 0);
    k_out3<<<dim3(KN/64, KB), 512, ko_lds, stream>>>(
        x, Et2, ws + o_cA, Mt2, bproj, out);
}